// Round 1
// 446.697 us; speedup vs baseline: 1.0130x; 1.0130x over previous
//
#include <hip/hip_runtime.h>
#include <hip/hip_bf16.h>

// CLIPAttention (B=16,T=1024,E=1024,H=16,DH=64) with 2D RoPE, bf16 MFMA path.
#define B_  16
#define T_  1024
#define E_  1024
#define H_  16
#define DH_ 64

typedef short s16x8 __attribute__((ext_vector_type(8)));   // 8 bf16 = 4 VGPRs (MFMA A/B frag)
typedef float f32x4 __attribute__((ext_vector_type(4)));   // MFMA C/D frag
typedef unsigned short u16x4 __attribute__((ext_vector_type(4)));  // 4 bf16 = 8B

__device__ __forceinline__ void async_cp16(const void* g, void* l) {
  __builtin_amdgcn_global_load_lds(
      (__attribute__((address_space(1))) unsigned int*)(g),
      (__attribute__((address_space(3))) unsigned int*)(l), 16, 0, 0);
}

__device__ __forceinline__ s16x8 frag8(const void* p) { return *(const s16x8*)p; }

__device__ __forceinline__ float fexp2(float x) {
#if __has_builtin(__builtin_amdgcn_exp2f)
  return __builtin_amdgcn_exp2f(x);
#else
  return exp2f(x);
#endif
}

__device__ __forceinline__ unsigned short f2bu(float x) {
  __hip_bfloat16 h = __float2bfloat16(x);
  return *reinterpret_cast<unsigned short*>(&h);
}

__device__ __forceinline__ float bu2f(unsigned short u) {
  __hip_bfloat16 h = *reinterpret_cast<__hip_bfloat16*>(&u);
  return __bfloat162float(h);
}

// ---------------- cast fp32 -> bf16 (vectorized, packed 8B store) ----------------
__global__ __launch_bounds__(256) void cast_f32_bf16(const float* __restrict__ in,
                                                     __hip_bfloat16* __restrict__ out,
                                                     int n4) {
  int i = blockIdx.x * 256 + threadIdx.x;
  if (i >= n4) return;
  float4 v = ((const float4*)in)[i];
  u16x4 pk = {f2bu(v.x), f2bu(v.y), f2bu(v.z), f2bu(v.w)};
  *(u16x4*)(out + (size_t)i * 4) = pk;
}

// ======================================================================
// 256x256 8-phase GEMM core (T1+T2+T3+T4+T5), BK=64, 512 threads = 8 waves (2Mx4N).
// LDS: 2 buffers x [A: 2 halves x 128x64 | B: 2 halves x 128x64] = 128 KiB.
// Region layout: row-major 128B rows; 16B group g of row r stored at group g^(r&7)
// (same proven XOR swizzle as before; applied by pre-swizzling the global source,
//  since global_load_lds writes base+lane*16 linearly).
// Schedule per K-tile j (buf d=j&1):
//   P0: read A(s=0)+B(t=0); issue A-half0 of j+1 -> buf d^1; bar; MFMA(0,0); bar
//   P1: read B(t=1);        issue A-half1 of j+1 -> buf d^1; bar; MFMA(0,1); bar
//   P2: read A(s=1);        issue B-half0 of j+2 -> buf d;   bar; MFMA(1,1); bar
//   P3:                     issue B-half1 of j+2 -> buf d;   bar; MFMA(1,0);
//       vmcnt(4) [never 0 mid-loop: 2 half-tiles stay in flight]; bar
// Region-safety: buf d's B regions retire at P1 (writes at P2/P3 OK); A regions
// retire at P2 (writes at next tile's P0/P1 OK). vmcnt(4) at tile end retires
// everything except the j+2 B halves -> all of tile j+1 is resident before its P0.
// ======================================================================
#define G8_ISSUE(SRC_, LOFF_, H_, D_, KT_)                                      \
  {                                                                             \
    _Pragma("unroll") for (int u_ = 0; u_ < 2; ++u_) {                          \
      const int ch_ = u_ * 8 + wave;                                            \
      async_cp16(SRC_ + (size_t)((H_)*128 + ch_ * 8) * 2048 + (KT_)*128,        \
                 smem + (D_)*65536 + (LOFF_) + (H_)*16384 + ch_ * 1024);        \
    }                                                                           \
  }

#define G8_READ_A(D_, S_)                                                       \
  {                                                                             \
    _Pragma("unroll") for (int i_ = 0; i_ < 4; ++i_) {                          \
      const char* rp_ = smem + (D_)*65536 + wrow * 16384 +                      \
                        ((S_)*64 + i_ * 16 + col) * 128;                        \
      af[i_][0] = frag8(rp_ + sw0);                                             \
      af[i_][1] = frag8(rp_ + sw1);                                             \
    }                                                                           \
  }

#define G8_READ_B(D_, T8_, BF_)                                                 \
  {                                                                             \
    _Pragma("unroll") for (int j_ = 0; j_ < 2; ++j_) {                          \
      const char* rp_ = smem + (D_)*65536 + 32768 + (wcol >> 1) * 16384 +       \
                        ((wcol & 1) * 64 + (T8_)*32 + j_ * 16 + col) * 128;     \
      BF_[j_][0] = frag8(rp_ + sw0);                                            \
      BF_[j_][1] = frag8(rp_ + sw1);                                            \
    }                                                                           \
  }

#define G8_MFMA(S_, T8_, BF_)                                                   \
  {                                                                             \
    __builtin_amdgcn_s_setprio(1);                                              \
    _Pragma("unroll") for (int i_ = 0; i_ < 4; ++i_)                            \
      _Pragma("unroll") for (int j_ = 0; j_ < 2; ++j_) {                        \
        acc[(S_)*4 + i_][(T8_)*2 + j_] = __builtin_amdgcn_mfma_f32_16x16x32_bf16( \
            af[i_][0], BF_[j_][0], acc[(S_)*4 + i_][(T8_)*2 + j_], 0, 0, 0);    \
        acc[(S_)*4 + i_][(T8_)*2 + j_] = __builtin_amdgcn_mfma_f32_16x16x32_bf16( \
            af[i_][1], BF_[j_][1], acc[(S_)*4 + i_][(T8_)*2 + j_], 0, 0, 0);    \
      }                                                                         \
    __builtin_amdgcn_s_setprio(0);                                              \
  }

#define G8_KTILE(D_, GA_, GB_, KTA_, KTB_, VM_)                                 \
  G8_READ_A(D_, 0)                                                              \
  G8_READ_B(D_, 0, bf0)                                                         \
  if (GA_) G8_ISSUE(Asrc, 0, 0, (D_) ^ 1, KTA_)                                 \
  __builtin_amdgcn_s_barrier();                                                 \
  G8_MFMA(0, 0, bf0)                                                            \
  __builtin_amdgcn_s_barrier();                                                 \
  G8_READ_B(D_, 1, bf1)                                                         \
  if (GA_) G8_ISSUE(Asrc, 0, 1, (D_) ^ 1, KTA_)                                 \
  __builtin_amdgcn_s_barrier();                                                 \
  G8_MFMA(0, 1, bf1)                                                            \
  __builtin_amdgcn_s_barrier();                                                 \
  G8_READ_A(D_, 1)                                                              \
  if (GB_) G8_ISSUE(Bsrc, 32768, 0, (D_), KTB_)                                 \
  __builtin_amdgcn_s_barrier();                                                 \
  G8_MFMA(1, 1, bf1)                                                            \
  __builtin_amdgcn_s_barrier();                                                 \
  if (GB_) G8_ISSUE(Bsrc, 32768, 1, (D_), KTB_)                                 \
  __builtin_amdgcn_s_barrier();                                                 \
  G8_MFMA(1, 0, bf0)                                                            \
  if (VM_) { asm volatile("s_waitcnt vmcnt(4)" ::: "memory"); }                 \
  else     { asm volatile("s_waitcnt vmcnt(0)" ::: "memory"); }                 \
  __builtin_amdgcn_s_barrier();

// K fixed at 1024 -> 16 K-tiles, main loop unrolled x2 (static buffer indices).
#define G8_CORE(APTR_, BPTR_)                                                   \
  __shared__ __align__(16) char smem[131072];                                   \
  const int tid = threadIdx.x;                                                  \
  const int lane = tid & 63, wave = tid >> 6;                                   \
  const int col = lane & 15, quad = lane >> 4;                                  \
  const int wrow = wave >> 2, wcol = wave & 3;                                  \
  const int r8 = lane >> 3;                                                     \
  const int gsw = (lane & 7) ^ r8;                                              \
  const int sw0 = (quad ^ (col & 7)) * 16;                                      \
  const int sw1 = ((quad + 4) ^ (col & 7)) * 16;                                \
  const char* Asrc = (const char*)(APTR_) + (size_t)(bm + r8) * 2048 + gsw * 16;\
  const char* Bsrc = (const char*)(BPTR_) + (size_t)(bn + r8) * 2048 + gsw * 16;\
  const f32x4 fzero = {0.f, 0.f, 0.f, 0.f};                                     \
  f32x4 acc[8][4];                                                              \
  _Pragma("unroll") for (int i_ = 0; i_ < 8; i_++)                              \
    _Pragma("unroll") for (int j_ = 0; j_ < 4; j_++) acc[i_][j_] = fzero;       \
  s16x8 af[4][2], bf0[2][2], bf1[2][2];                                         \
  G8_ISSUE(Bsrc, 32768, 0, 0, 0)                                                \
  G8_ISSUE(Bsrc, 32768, 1, 0, 0)                                                \
  G8_ISSUE(Asrc, 0, 0, 0, 0)                                                    \
  G8_ISSUE(Asrc, 0, 1, 0, 0)                                                    \
  G8_ISSUE(Bsrc, 32768, 0, 1, 1)                                                \
  G8_ISSUE(Bsrc, 32768, 1, 1, 1)                                                \
  asm volatile("s_waitcnt vmcnt(4)" ::: "memory");                              \
  __builtin_amdgcn_s_barrier();                                                 \
  _Pragma("clang loop unroll(disable)") for (int it = 0; it < 8; ++it) {        \
    const bool g7 = (it < 7);                                                   \
    G8_KTILE(0, true, g7, 2 * it + 1, 2 * it + 2, g7)                           \
    G8_KTILE(1, g7, g7, 2 * it + 2, 2 * it + 3, g7)                             \
  }

// ---------------- fused QKV GEMM (256x256 tiles, grid 64x12=768) ----------------
__global__ __launch_bounds__(512, 2) void gemm_qkv(const __hip_bfloat16* __restrict__ A,
                                                   const __hip_bfloat16* __restrict__ Wqkv,
                                                   const float* __restrict__ bq,
                                                   const float* __restrict__ bk,
                                                   const float* __restrict__ bv,
                                                   __hip_bfloat16* __restrict__ Qb,
                                                   __hip_bfloat16* __restrict__ Kb,
                                                   __hip_bfloat16* __restrict__ Vt) {
  const int wg = (blockIdx.x & 7) * 96 + (blockIdx.x >> 3);  // XCD swizzle (768%8==0)
  const int bm = (wg & 63) << 8;
  const int bn = (wg >> 6) << 8;
  G8_CORE(A, Wqkv)

  const int seg = bn >> 10;  // 0=Q 1=K 2=V (BN=256 divides 1024 -> uniform per block)
  const float* bp = (seg == 0) ? bq : (seg == 1) ? bk : bv;
  const int nbase = (bn & 1023) + wcol * 64;
  float bcol[4];
#pragma unroll
  for (int j = 0; j < 4; j++) bcol[j] = bp[nbase + j * 16 + col];
  if (seg < 2) {
    __hip_bfloat16* P = (seg == 0) ? Qb : Kb;
#pragma unroll
    for (int mi = 0; mi < 8; mi++) {
      const int gr0 = bm + wrow * 128 + mi * 16 + quad * 4;
#pragma unroll
      for (int ni = 0; ni < 4; ni++) {
        const int nc = nbase + ni * 16 + col;
#pragma unroll
        for (int r = 0; r < 4; r++)
          P[(size_t)(gr0 + r) * 1024 + nc] = __float2bfloat16(acc[mi][ni][r] + bcol[ni]);
      }
    }
  } else {
    // V transposed (b,h,d,t): 4 consecutive t per lane -> packed 8B store
#pragma unroll
    for (int mi = 0; mi < 8; mi++) {
      const int gr0 = bm + wrow * 128 + mi * 16 + quad * 4;
      const int bb = gr0 >> 10, tt = gr0 & 1023;
#pragma unroll
      for (int ni = 0; ni < 4; ni++) {
        const int nc = nbase + ni * 16 + col;
        const int hh = nc >> 6, dd = nc & 63;
        u16x4 pk = {f2bu(acc[mi][ni][0] + bcol[ni]), f2bu(acc[mi][ni][1] + bcol[ni]),
                    f2bu(acc[mi][ni][2] + bcol[ni]), f2bu(acc[mi][ni][3] + bcol[ni])};
        *(u16x4*)(Vt + (((size_t)bb * H_ + hh) * DH_ + dd) * T_ + tt) = pk;
      }
    }
  }
}

// ---------------- output-proj GEMM: fp32 out (grid 64x4=256) ----------------
__global__ __launch_bounds__(512, 2) void gemm_out(const __hip_bfloat16* __restrict__ A,
                                                   const __hip_bfloat16* __restrict__ Bw,
                                                   const float* __restrict__ bias,
                                                   float* __restrict__ Cout) {
  const int wg = (blockIdx.x & 7) * 32 + (blockIdx.x >> 3);  // XCD swizzle (256%8==0)
  const int bm = (wg & 63) << 8;
  const int bn = (wg >> 6) << 8;
  G8_CORE(A, Bw)

  const int nbase = bn + wcol * 64;
  float bcol[4];
#pragma unroll
  for (int j = 0; j < 4; j++) bcol[j] = bias[nbase + j * 16 + col];
#pragma unroll
  for (int mi = 0; mi < 8; mi++) {
    const int gr0 = bm + wrow * 128 + mi * 16 + quad * 4;
#pragma unroll
    for (int ni = 0; ni < 4; ni++) {
      const int gcol = nbase + ni * 16 + col;
#pragma unroll
      for (int r = 0; r < 4; r++)
        Cout[(size_t)(gr0 + r) * 1024 + gcol] = acc[mi][ni][r] + bcol[ni];
    }
  }
}

// ---------------- 2D RoPE, in-place; Q additionally scaled by 0.125*log2(e) ----------------
__global__ __launch_bounds__(256) void rope2d(__hip_bfloat16* __restrict__ Q,
                                              __hip_bfloat16* __restrict__ K,
                                              const int* __restrict__ pos) {
  const int row = blockIdx.x;   // b*T + t
  const int t   = threadIdx.x;  // elements 4t..4t+3 (2 rotation pairs)
  const float ph = (float)pos[row * 2 + 0];
  const float pw = (float)pos[row * 2 + 1];
  const int pd = (2 * t) & 31;
  float cs[2], sn[2];
#pragma unroll
  for (int i = 0; i < 2; i++) {
    int pdi = pd + i;
    int f = pdi & 15;
    float p = (pdi & 16) ? pw : ph;
    float inv = __expf((float)f * (-1.1512925464970229f));  // 10000^(-f/8)
    float ang = p * inv;
    __sincosf(ang, &sn[i], &cs[i]);
  }
  const float QSC = 0.18033688011112043f;  // 0.125 * log2(e): softmax scale folded, exp2-ready
  size_t base = (size_t)row * E_ + 4 * t;
  {
    u16x4 q4 = *(u16x4*)(Q + base);
    float e0 = bu2f(q4[0]), e1 = bu2f(q4[1]), e2 = bu2f(q4[2]), e3 = bu2f(q4[3]);
    u16x4 o4 = {f2bu((e0 * cs[0] - e1 * sn[0]) * QSC),
                f2bu((e1 * cs[0] + e0 * sn[0]) * QSC),
                f2bu((e2 * cs[1] - e3 * sn[1]) * QSC),
                f2bu((e3 * cs[1] + e2 * sn[1]) * QSC)};
    *(u16x4*)(Q + base) = o4;
  }
  {
    u16x4 k4 = *(u16x4*)(K + base);
    float e0 = bu2f(k4[0]), e1 = bu2f(k4[1]), e2 = bu2f(k4[2]), e3 = bu2f(k4[3]);
    u16x4 o4 = {f2bu(e0 * cs[0] - e1 * sn[0]),
                f2bu(e1 * cs[0] + e0 * sn[0]),
                f2bu(e2 * cs[1] - e3 * sn[1]),
                f2bu(e3 * cs[1] + e2 * sn[1])};
    *(u16x4*)(K + base) = o4;
  }
}

// ---------------- flash attention, S^T formulation, fixed-max softmax ----------------
// (unchanged from 445us baseline)
__global__ __launch_bounds__(256, 3) void attn_flash(const __hip_bfloat16* __restrict__ Q,
                                                     const __hip_bfloat16* __restrict__ Kt,
                                                     const __hip_bfloat16* __restrict__ Vt,
                                                     __hip_bfloat16* __restrict__ Oa) {
  __shared__ __align__(16) __hip_bfloat16 QP[128 * 72];  // 144B rows: Q tile, then P^T scratch
  __shared__ __align__(16) __hip_bfloat16 Ks[64 * 72];   // rows = key, 64 d (128B) + pad
  __shared__ __align__(16) __hip_bfloat16 Vs[64 * 72];   // rows = d, 64 keys (128B) + pad

  const int bid = blockIdx.x;          // 2048 = 256 (b,h) x 8 q-tiles
  const int bh = bid >> 3;
  const int b = bh >> 4, h = bh & 15;
  const int qt = bid & 7;
  const int tid = threadIdx.x;
  const int lane = tid & 63, wave = tid >> 6;
  const int col = lane & 15, quad = lane >> 4;

  const size_t qrow0 = (size_t)b * T_ + qt * 128;

  // stage Q tile (128 rows x 128B)
#pragma unroll
  for (int cc = 0; cc < 4; ++cc) {
    int c = tid + cc * 256;
    int r = c >> 3, k8 = c & 7;
    const float4* src = (const float4*)((const char*)(Q + (qrow0 + r) * E_ + h * DH_)) + k8;
    *(float4*)((char*)QP + r * 144 + k8 * 16) = *src;
  }

  const f32x4 fzero = {0.f, 0.f, 0.f, 0.f};
  f32x4 o[2][4];           // o[g][jm][r] = O^T[d = jm*16+quad*4+r][q = col] (per g q-group)
  float lr[2] = {0.f, 0.f};
#pragma unroll
  for (int g = 0; g < 2; g++)
#pragma unroll
    for (int j = 0; j < 4; j++) o[g][j] = fzero;
  s16x8 qf[2][2];
  char* Pw = (char*)QP + wave * 32 * 144;  // this wave's 32 P rows (q-major, 144B pitch)

  for (int kt2 = 0; kt2 < 16; ++kt2) {
    __syncthreads();
    const int kb = kt2 * 64;
#pragma unroll
    for (int cc = 0; cc < 4; ++cc) {
      int c = tid + cc * 256;
      if (c < 512) {
        int r = c >> 3, k8 = c & 7;
        const float4* src = (const float4*)((const char*)(Kt + ((size_t)b * T_ + kb + r) * E_ + h * DH_)) + k8;
        *(float4*)((char*)Ks + r * 144 + k8 * 16) = *src;
      } else {
        int c2 = c - 512;
        int d = c2 >> 3, k8 = c2 & 7;
        const float4* src = (const float4*)((const char*)(Vt + (((size_t)b * H_ + h) * DH_ + d) * T_ + kb)) + k8;
        *(float4*)((char*)Vs + d * 144 + k8 * 16) = *src;
      }
    }
    __syncthreads();
    if (kt2 == 0) {
#pragma unroll
      for (int g = 0; g < 2; g++) {
        qf[g][0] = frag8((const char*)QP + (g * 64 + wave * 16 + col) * 144 + quad * 16);
        qf[g][1] = frag8((const char*)QP + (g * 64 + wave * 16 + col) * 144 + 64 + quad * 16);
      }
      __syncthreads();  // all Q reads done before any wave's P writes clobber QP
    }
    // K A-frags (shared across g)
    s16x8 kf[4][2];
#pragma unroll
    for (int ktile = 0; ktile < 4; ktile++) {
      kf[ktile][0] = frag8((const char*)Ks + (ktile * 16 + col) * 144 + quad * 16);
      kf[ktile][1] = frag8((const char*)Ks + (ktile * 16 + col) * 144 + 64 + quad * 16);
    }
    // S^T tiles: rows=key (quad*4+r), cols=q (col); exp2; pack 4 keys -> b64 write
#pragma unroll
    for (int g = 0; g < 2; g++) {
#pragma unroll
      for (int ktile = 0; ktile < 4; ktile++) {
        f32x4 d = fzero;
        d = __builtin_amdgcn_mfma_f32_16x16x32_bf16(kf[ktile][0], qf[g][0], d, 0, 0, 0);
        d = __builtin_amdgcn_mfma_f32_16x16x32_bf16(kf[ktile][1], qf[g][1], d, 0, 0, 0);
        float p0 = fexp2(d[0]), p1 = fexp2(d[1]), p2 = fexp2(d[2]), p3 = fexp2(d[3]);
        lr[g] += (p0 + p1) + (p2 + p3);
        u16x4 pk = {f2bu(p0), f2bu(p1), f2bu(p2), f2bu(p3)};
        *(u16x4*)(Pw + (g * 16 + col) * 144 + ktile * 32 + quad * 8) = pk;
      }
    }
    // V A-frags (shared across g)
    s16x8 vf[4][2];
#pragma unroll
    for (int jm = 0; jm < 4; jm++) {
      vf[jm][0] = frag8((const char*)Vs + (jm * 16 + col) * 144 + quad * 16);
      vf[jm][1] = frag8((const char*)Vs + (jm * 16 + col) * 144 + 64 + quad * 16);
    }
    // O^T += V^T P^T (P re-read as B-operand; same-wave DS ops are in-order)
#pragma unroll
    for (int g = 0; g < 2; g++) {
      s16x8 pf0 = frag8(Pw + (g * 16 + col) * 144 + quad * 16);
      s16x8 pf1 = frag8(Pw + (g * 16 + col) * 144 + 64 + quad * 16);
#pragma unroll
      for (int jm = 0; jm < 4; jm++) {
        o[g][jm] = __builtin_amdgcn_mfma_f32_16x16x32_bf16(vf[jm][0], pf0, o[g][jm], 0, 0, 0);
        o[g][jm] = __builtin_amdgcn_mfma_f32_16x16x32_bf16(vf[jm][1], pf1, o[g][jm], 0, 0, 0);
      }
    }
  }
  // l lives per (q=col): quads hold disjoint key subsets -> reduce across quads
#pragma unroll
  for (int g = 0; g < 2; g++) {
    lr[g] += __shfl_xor(lr[g], 16, 64);
    lr[g] += __shfl_xor(lr[g], 32, 64);
  }
  // normalize + packed store: row = q, 4 consecutive d per lane -> 8B stores
#pragma unroll
  for (int g = 0; g < 2; g++) {
    float invl = 1.f / lr[g];
    size_t grow = qrow0 + g * 64 + wave * 16 + col;
    char* obase = (char*)(Oa + grow * E_ + h * DH_);
#pragma unroll
    for (int jm = 0; jm < 4; jm++) {
      u16x4 pk = {f2bu(o[g][jm][0] * invl), f2bu(o[g][jm][1] * invl),
                  f2bu(o[g][jm][2] * invl), f2bu(o[g][jm][3] * invl)};
      *(u16x4*)(obase + jm * 32 + quad * 8) = pk;
    }
  }
}

extern "C" void kernel_launch(void* const* d_in, const int* in_sizes, int n_in,
                              void* d_out, int out_size, void* d_ws, size_t ws_size,
                              hipStream_t stream) {
  const float* X   = (const float*)d_in[0];
  const int*   pos = (const int*)d_in[1];
  const float* Wq  = (const float*)d_in[2];
  const float* bq  = (const float*)d_in[3];
  const float* Wk  = (const float*)d_in[4];
  const float* bk  = (const float*)d_in[5];
  const float* Wv  = (const float*)d_in[6];
  const float* bv  = (const float*)d_in[7];
  const float* Wo  = (const float*)d_in[8];
  const float* bo  = (const float*)d_in[9];
  float* out = (float*)d_out;

  char* ws = (char*)d_ws;
  const size_t MB = 1024 * 1024;
  __hip_bfloat16* Xb    = (__hip_bfloat16*)(ws + 0 * MB);    // 32 MB
  __hip_bfloat16* Qb    = (__hip_bfloat16*)(ws + 32 * MB);   // 32 MB
  __hip_bfloat16* Kb    = (__hip_bfloat16*)(ws + 64 * MB);   // 32 MB
  __hip_bfloat16* Vtb   = (__hip_bfloat16*)(ws + 96 * MB);   // 32 MB (b,h,d,t)
  __hip_bfloat16* Wqkvb = (__hip_bfloat16*)(ws + 128 * MB);  // 6 MB (3072x1024)
  __hip_bfloat16* Wob   = (__hip_bfloat16*)(ws + 136 * MB);  // 2 MB
  __hip_bfloat16* Ab    = Xb;  // reuse: X dead after QKV projection

  cast_f32_bf16<<<16384, 256, 0, stream>>>(X,  Xb,  4194304);
  cast_f32_bf16<<<1024,  256, 0, stream>>>(Wq, Wqkvb,           262144);
  cast_f32_bf16<<<1024,  256, 0, stream>>>(Wk, Wqkvb + 1048576, 262144);
  cast_f32_bf16<<<1024,  256, 0, stream>>>(Wv, Wqkvb + 2097152, 262144);
  cast_f32_bf16<<<1024,  256, 0, stream>>>(Wo, Wob,             262144);

  gemm_qkv<<<768, 512, 0, stream>>>(Xb, Wqkvb, bq, bk, bv, Qb, Kb, Vtb);

  rope2d<<<16384, 256, 0, stream>>>(Qb, Kb, pos);
  attn_flash<<<2048, 256, 0, stream>>>(Qb, Kb, Vtb, Ab);

  gemm_out<<<256, 512, 0, stream>>>(Ab, Wob, bo, out);
}

// Round 2
// 433.760 us; speedup vs baseline: 1.0432x; 1.0298x over previous
//
#include <hip/hip_runtime.h>
#include <hip/hip_bf16.h>

// CLIPAttention (B=16,T=1024,E=1024,H=16,DH=64) with 2D RoPE, bf16 MFMA path.
#define B_  16
#define T_  1024
#define E_  1024
#define H_  16
#define DH_ 64

typedef short s16x8 __attribute__((ext_vector_type(8)));   // 8 bf16 = 4 VGPRs (MFMA A/B frag)
typedef float f32x4 __attribute__((ext_vector_type(4)));   // MFMA C/D frag
typedef unsigned short u16x4 __attribute__((ext_vector_type(4)));  // 4 bf16 = 8B

__device__ __forceinline__ void async_cp16(const void* g, void* l) {
  __builtin_amdgcn_global_load_lds(
      (__attribute__((address_space(1))) unsigned int*)(g),
      (__attribute__((address_space(3))) unsigned int*)(l), 16, 0, 0);
}

__device__ __forceinline__ s16x8 frag8(const void* p) { return *(const s16x8*)p; }

__device__ __forceinline__ float fexp2(float x) {
#if __has_builtin(__builtin_amdgcn_exp2f)
  return __builtin_amdgcn_exp2f(x);
#else
  return exp2f(x);
#endif
}

__device__ __forceinline__ unsigned short f2bu(float x) {
  __hip_bfloat16 h = __float2bfloat16(x);
  return *reinterpret_cast<unsigned short*>(&h);
}

__device__ __forceinline__ float bu2f(unsigned short u) {
  __hip_bfloat16 h = *reinterpret_cast<__hip_bfloat16*>(&u);
  return __bfloat162float(h);
}

// ---------------- single fused cast fp32 -> bf16 (X + 4 weight mats) ----------------
// grid = 16384 (X) + 4*1024 (Wq,Wk,Wv,Wo) = 20480 blocks x 256 thr, 1 float4/thread.
__global__ __launch_bounds__(256) void cast_all(const float* __restrict__ X,
                                                const float* __restrict__ Wq,
                                                const float* __restrict__ Wk,
                                                const float* __restrict__ Wv,
                                                const float* __restrict__ Wo,
                                                __hip_bfloat16* __restrict__ Xb,
                                                __hip_bfloat16* __restrict__ Wqkvb,
                                                __hip_bfloat16* __restrict__ Wob) {
  const int bid = blockIdx.x;
  const float* src;
  __hip_bfloat16* dst;
  int i;
  if (bid < 16384) {
    src = X; dst = Xb; i = bid * 256 + threadIdx.x;
  } else {
    const int wb = bid - 16384;
    const int w = wb >> 10;
    src = (w == 0) ? Wq : (w == 1) ? Wk : (w == 2) ? Wv : Wo;
    dst = (w == 3) ? Wob : Wqkvb + (size_t)w * 1048576;
    i = (wb & 1023) * 256 + threadIdx.x;
  }
  float4 v = ((const float4*)src)[i];
  u16x4 pk = {f2bu(v.x), f2bu(v.y), f2bu(v.z), f2bu(v.w)};
  *(u16x4*)(dst + (size_t)i * 4) = pk;
}

// ======================================================================
// 256x256 8-phase GEMM core (T1+T2+T3+T4+T5), BK=64, 512 threads = 8 waves (2Mx4N).
// LDS: 2 buffers x [A: 2 halves x 128x64 | B: 2 halves x 128x64] = 128 KiB.
// (unchanged from R1 - verified correct; MfmaUtil-capped at ~34% by K=1024 shape)
// ======================================================================
#define G8_ISSUE(SRC_, LOFF_, H_, D_, KT_)                                      \
  {                                                                             \
    _Pragma("unroll") for (int u_ = 0; u_ < 2; ++u_) {                          \
      const int ch_ = u_ * 8 + wave;                                            \
      async_cp16(SRC_ + (size_t)((H_)*128 + ch_ * 8) * 2048 + (KT_)*128,        \
                 smem + (D_)*65536 + (LOFF_) + (H_)*16384 + ch_ * 1024);        \
    }                                                                           \
  }

#define G8_READ_A(D_, S_)                                                       \
  {                                                                             \
    _Pragma("unroll") for (int i_ = 0; i_ < 4; ++i_) {                          \
      const char* rp_ = smem + (D_)*65536 + wrow * 16384 +                      \
                        ((S_)*64 + i_ * 16 + col) * 128;                        \
      af[i_][0] = frag8(rp_ + sw0);                                             \
      af[i_][1] = frag8(rp_ + sw1);                                             \
    }                                                                           \
  }

#define G8_READ_B(D_, T8_, BF_)                                                 \
  {                                                                             \
    _Pragma("unroll") for (int j_ = 0; j_ < 2; ++j_) {                          \
      const char* rp_ = smem + (D_)*65536 + 32768 + (wcol >> 1) * 16384 +       \
                        ((wcol & 1) * 64 + (T8_)*32 + j_ * 16 + col) * 128;     \
      BF_[j_][0] = frag8(rp_ + sw0);                                            \
      BF_[j_][1] = frag8(rp_ + sw1);                                            \
    }                                                                           \
  }

#define G8_MFMA(S_, T8_, BF_)                                                   \
  {                                                                             \
    __builtin_amdgcn_s_setprio(1);                                              \
    _Pragma("unroll") for (int i_ = 0; i_ < 4; ++i_)                            \
      _Pragma("unroll") for (int j_ = 0; j_ < 2; ++j_) {                        \
        acc[(S_)*4 + i_][(T8_)*2 + j_] = __builtin_amdgcn_mfma_f32_16x16x32_bf16( \
            af[i_][0], BF_[j_][0], acc[(S_)*4 + i_][(T8_)*2 + j_], 0, 0, 0);    \
        acc[(S_)*4 + i_][(T8_)*2 + j_] = __builtin_amdgcn_mfma_f32_16x16x32_bf16( \
            af[i_][1], BF_[j_][1], acc[(S_)*4 + i_][(T8_)*2 + j_], 0, 0, 0);    \
      }                                                                         \
    __builtin_amdgcn_s_setprio(0);                                              \
  }

#define G8_KTILE(D_, GA_, GB_, KTA_, KTB_, VM_)                                 \
  G8_READ_A(D_, 0)                                                              \
  G8_READ_B(D_, 0, bf0)                                                         \
  if (GA_) G8_ISSUE(Asrc, 0, 0, (D_) ^ 1, KTA_)                                 \
  __builtin_amdgcn_s_barrier();                                                 \
  G8_MFMA(0, 0, bf0)                                                            \
  __builtin_amdgcn_s_barrier();                                                 \
  G8_READ_B(D_, 1, bf1)                                                         \
  if (GA_) G8_ISSUE(Asrc, 0, 1, (D_) ^ 1, KTA_)                                 \
  __builtin_amdgcn_s_barrier();                                                 \
  G8_MFMA(0, 1, bf1)                                                            \
  __builtin_amdgcn_s_barrier();                                                 \
  G8_READ_A(D_, 1)                                                              \
  if (GB_) G8_ISSUE(Bsrc, 32768, 0, (D_), KTB_)                                 \
  __builtin_amdgcn_s_barrier();                                                 \
  G8_MFMA(1, 1, bf1)                                                            \
  __builtin_amdgcn_s_barrier();                                                 \
  if (GB_) G8_ISSUE(Bsrc, 32768, 1, (D_), KTB_)                                 \
  __builtin_amdgcn_s_barrier();                                                 \
  G8_MFMA(1, 0, bf0)                                                            \
  if (VM_) { asm volatile("s_waitcnt vmcnt(4)" ::: "memory"); }                 \
  else     { asm volatile("s_waitcnt vmcnt(0)" ::: "memory"); }                 \
  __builtin_amdgcn_s_barrier();

// K fixed at 1024 -> 16 K-tiles, main loop unrolled x2 (static buffer indices).
#define G8_CORE(APTR_, BPTR_)                                                   \
  __shared__ __align__(16) char smem[131072];                                   \
  const int tid = threadIdx.x;                                                  \
  const int lane = tid & 63, wave = tid >> 6;                                   \
  const int col = lane & 15, quad = lane >> 4;                                  \
  const int wrow = wave >> 2, wcol = wave & 3;                                  \
  const int r8 = lane >> 3;                                                     \
  const int gsw = (lane & 7) ^ r8;                                              \
  const int sw0 = (quad ^ (col & 7)) * 16;                                      \
  const int sw1 = ((quad + 4) ^ (col & 7)) * 16;                                \
  const char* Asrc = (const char*)(APTR_) + (size_t)(bm + r8) * 2048 + gsw * 16;\
  const char* Bsrc = (const char*)(BPTR_) + (size_t)(bn + r8) * 2048 + gsw * 16;\
  const f32x4 fzero = {0.f, 0.f, 0.f, 0.f};                                     \
  f32x4 acc[8][4];                                                              \
  _Pragma("unroll") for (int i_ = 0; i_ < 8; i_++)                              \
    _Pragma("unroll") for (int j_ = 0; j_ < 4; j_++) acc[i_][j_] = fzero;       \
  s16x8 af[4][2], bf0[2][2], bf1[2][2];                                         \
  G8_ISSUE(Bsrc, 32768, 0, 0, 0)                                                \
  G8_ISSUE(Bsrc, 32768, 1, 0, 0)                                                \
  G8_ISSUE(Asrc, 0, 0, 0, 0)                                                    \
  G8_ISSUE(Asrc, 0, 1, 0, 0)                                                    \
  G8_ISSUE(Bsrc, 32768, 0, 1, 1)                                                \
  G8_ISSUE(Bsrc, 32768, 1, 1, 1)                                                \
  asm volatile("s_waitcnt vmcnt(4)" ::: "memory");                              \
  __builtin_amdgcn_s_barrier();                                                 \
  _Pragma("clang loop unroll(disable)") for (int it = 0; it < 8; ++it) {        \
    const bool g7 = (it < 7);                                                   \
    G8_KTILE(0, true, g7, 2 * it + 1, 2 * it + 2, g7)                           \
    G8_KTILE(1, g7, g7, 2 * it + 2, 2 * it + 3, g7)                             \
  }

// ---------------- fused QKV GEMM + bias + 2D RoPE epilogue ----------------
// Q/K get RoPE applied in-register before store (rope2d kernel eliminated).
// Pairs (2i,2i+1) of the rotation are adjacent LANES (nc = nbase+ni*16+col)
// -> one __shfl_xor(v,1). Angles: p in [0,32), f in [0,16) -> 512-entry
// cos/sin LDS table built in the freed GEMM smem (1 sincos per thread).
__global__ __launch_bounds__(512, 2) void gemm_qkv(const __hip_bfloat16* __restrict__ A,
                                                   const __hip_bfloat16* __restrict__ Wqkv,
                                                   const float* __restrict__ bq,
                                                   const float* __restrict__ bk,
                                                   const float* __restrict__ bv,
                                                   const int* __restrict__ pos,
                                                   __hip_bfloat16* __restrict__ Qb,
                                                   __hip_bfloat16* __restrict__ Kb,
                                                   __hip_bfloat16* __restrict__ Vt) {
  const int wg = (blockIdx.x & 7) * 96 + (blockIdx.x >> 3);  // XCD swizzle (768%8==0)
  const int bm = (wg & 63) << 8;
  const int bn = (wg >> 6) << 8;
  G8_CORE(A, Wqkv)

  const int seg = bn >> 10;  // 0=Q 1=K 2=V (BN=256 divides 1024 -> uniform per block)
  const float* bp = (seg == 0) ? bq : (seg == 1) ? bk : bv;
  const int nbase = (bn & 1023) + wcol * 64;
  float bcol[4];
#pragma unroll
  for (int j = 0; j < 4; j++) bcol[j] = bp[nbase + j * 16 + col];
  if (seg < 2) {
    // ---- build sincos table in freed smem: tab[p*16+f] = {cos, sin} of p*10000^(-f/8)
    __syncthreads();
    float2* tab = (float2*)smem;
    {
      const int p_ = tid >> 4, f_ = tid & 15;
      const float inv = __expf((float)f_ * -1.1512925464970229f);
      float s_, c_;
      __sincosf((float)p_ * inv, &s_, &c_);
      tab[tid] = make_float2(c_, s_);
    }
    __syncthreads();
    const float SCL = (seg == 0) ? 0.18033688011112043f : 1.0f;  // Q: 0.125*log2(e)
    __hip_bfloat16* P = (seg == 0) ? Qb : Kb;
    const int codd = col & 1;
#pragma unroll
    for (int mi = 0; mi < 8; mi++) {
      const int gr0 = bm + wrow * 128 + mi * 16 + quad * 4;
#pragma unroll
      for (int r = 0; r < 4; r++) {
        const int grow = gr0 + r;
        const int iph = pos[grow * 2 + 0];
        const int ipw = pos[grow * 2 + 1];
#pragma unroll
        for (int ni = 0; ni < 4; ni++) {
          const int f = ((ni & 1) << 3) + (col >> 1);
          const int p_ = (ni >= 2) ? ipw : iph;
          const float2 cs = tab[p_ * 16 + f];
          const float v = acc[mi][ni][r] + bcol[ni];
          const float vp = __shfl_xor(v, 1, 64);
          const float rot = codd ? (v * cs.x + vp * cs.y) : (v * cs.x - vp * cs.y);
          P[(size_t)grow * 1024 + nbase + ni * 16 + col] = __float2bfloat16(rot * SCL);
        }
      }
    }
  } else {
    // V transposed (b,h,d,t): 4 consecutive t per lane -> packed 8B store
#pragma unroll
    for (int mi = 0; mi < 8; mi++) {
      const int gr0 = bm + wrow * 128 + mi * 16 + quad * 4;
      const int bb = gr0 >> 10, tt = gr0 & 1023;
#pragma unroll
      for (int ni = 0; ni < 4; ni++) {
        const int nc = nbase + ni * 16 + col;
        const int hh = nc >> 6, dd = nc & 63;
        u16x4 pk = {f2bu(acc[mi][ni][0] + bcol[ni]), f2bu(acc[mi][ni][1] + bcol[ni]),
                    f2bu(acc[mi][ni][2] + bcol[ni]), f2bu(acc[mi][ni][3] + bcol[ni])};
        *(u16x4*)(Vt + (((size_t)bb * H_ + hh) * DH_ + dd) * T_ + tt) = pk;
      }
    }
  }
}

// ---------------- output-proj GEMM: fp32 out (grid 64x4=256) ----------------
__global__ __launch_bounds__(512, 2) void gemm_out(const __hip_bfloat16* __restrict__ A,
                                                   const __hip_bfloat16* __restrict__ Bw,
                                                   const float* __restrict__ bias,
                                                   float* __restrict__ Cout) {
  const int wg = (blockIdx.x & 7) * 32 + (blockIdx.x >> 3);  // XCD swizzle (256%8==0)
  const int bm = (wg & 63) << 8;
  const int bn = (wg >> 6) << 8;
  G8_CORE(A, Bw)

  const int nbase = bn + wcol * 64;
  float bcol[4];
#pragma unroll
  for (int j = 0; j < 4; j++) bcol[j] = bias[nbase + j * 16 + col];
#pragma unroll
  for (int mi = 0; mi < 8; mi++) {
    const int gr0 = bm + wrow * 128 + mi * 16 + quad * 4;
#pragma unroll
    for (int ni = 0; ni < 4; ni++) {
      const int gcol = nbase + ni * 16 + col;
#pragma unroll
      for (int r = 0; r < 4; r++)
        Cout[(size_t)(gr0 + r) * 1024 + gcol] = acc[mi][ni][r] + bcol[ni];
    }
  }
}

// ---------------- flash attention, S^T formulation, fixed-max softmax ----------------
// R2 changes: (1) XCD-locality swizzle -- all 8 q-tiles of one (b,h) share bid%8
// (same XCD L2; K/V fetched from HBM once per XCD instead of 8x across XCDs);
// (2) T14 async K/V staging -- next tile's K/V loaded into registers during the
// current tile's compute, written to LDS after the barrier (HBM/L2 latency hidden).
__global__ __launch_bounds__(256, 3) void attn_flash(const __hip_bfloat16* __restrict__ Q,
                                                     const __hip_bfloat16* __restrict__ Kt,
                                                     const __hip_bfloat16* __restrict__ Vt,
                                                     __hip_bfloat16* __restrict__ Oa) {
  __shared__ __align__(16) __hip_bfloat16 QP[128 * 72];  // 144B rows: Q tile, then P^T scratch
  __shared__ __align__(16) __hip_bfloat16 Ks[64 * 72];   // rows = key, 64 d (128B) + pad
  __shared__ __align__(16) __hip_bfloat16 Vs[64 * 72];   // rows = d, 64 keys (128B) + pad

  const int bid = blockIdx.x;          // 2048 = 256 (b,h) x 8 q-tiles
  // XCD-locality swizzle: xcd = bid&7 owns bh in [xcd*32, xcd*32+32); the 8 q-tiles
  // of a bh are adjacent slots -> co-resident on one XCD -> K/V L2-shared.
  const int xcd = bid & 7, slot = bid >> 3;
  const int bh = xcd * 32 + (slot >> 3);
  const int qt = slot & 7;
  const int b = bh >> 4, h = bh & 15;
  const int tid = threadIdx.x;
  const int lane = tid & 63, wave = tid >> 6;
  const int col = lane & 15, quad = lane >> 4;

  const size_t qrow0 = (size_t)b * T_ + qt * 128;

  // stage Q tile (128 rows x 128B)
#pragma unroll
  for (int cc = 0; cc < 4; ++cc) {
    int c = tid + cc * 256;
    int r = c >> 3, k8 = c & 7;
    const float4* src = (const float4*)((const char*)(Q + (qrow0 + r) * E_ + h * DH_)) + k8;
    *(float4*)((char*)QP + r * 144 + k8 * 16) = *src;
  }

  // per-thread K/V reg-staging addresses
  const char* Ksrc = (const char*)(Kt + (size_t)b * T_ * E_ + h * DH_);
  const char* Vsrc = (const char*)(Vt + ((size_t)b * H_ + h) * DH_ * (size_t)T_);
  const int sr = tid >> 3, sk8 = tid & 7;  // 256 threads: 32 rows x 8 16B-groups
  float4 kv[4];
#define LOADKV(KB_)                                                                  \
  {                                                                                  \
    kv[0] = *(const float4*)(Ksrc + (size_t)((KB_) + sr) * 2048 + sk8 * 16);         \
    kv[1] = *(const float4*)(Ksrc + (size_t)((KB_) + 32 + sr) * 2048 + sk8 * 16);    \
    kv[2] = *(const float4*)(Vsrc + (size_t)sr * 2048 + (KB_)*2 + sk8 * 16);         \
    kv[3] = *(const float4*)(Vsrc + (size_t)(32 + sr) * 2048 + (KB_)*2 + sk8 * 16);  \
  }
#define WRITEKV()                                                                    \
  {                                                                                  \
    *(float4*)((char*)Ks + sr * 144 + sk8 * 16) = kv[0];                             \
    *(float4*)((char*)Ks + (32 + sr) * 144 + sk8 * 16) = kv[1];                      \
    *(float4*)((char*)Vs + sr * 144 + sk8 * 16) = kv[2];                             \
    *(float4*)((char*)Vs + (32 + sr) * 144 + sk8 * 16) = kv[3];                      \
  }

  const f32x4 fzero = {0.f, 0.f, 0.f, 0.f};
  f32x4 o[2][4];           // o[g][jm][r] = O^T[d = jm*16+quad*4+r][q = col] (per g q-group)
  float lr[2] = {0.f, 0.f};
#pragma unroll
  for (int g = 0; g < 2; g++)
#pragma unroll
    for (int j = 0; j < 4; j++) o[g][j] = fzero;
  s16x8 qf[2][2];
  char* Pw = (char*)QP + wave * 32 * 144;  // this wave's 32 P rows (q-major, 144B pitch)

  LOADKV(0)
  for (int kt2 = 0; kt2 < 16; ++kt2) {
    __syncthreads();          // prev iter's LDS reads done -> safe to overwrite K/V
    WRITEKV()
    __syncthreads();
    if (kt2 == 0) {
#pragma unroll
      for (int g = 0; g < 2; g++) {
        qf[g][0] = frag8((const char*)QP + (g * 64 + wave * 16 + col) * 144 + quad * 16);
        qf[g][1] = frag8((const char*)QP + (g * 64 + wave * 16 + col) * 144 + 64 + quad * 16);
      }
      __syncthreads();  // all Q reads done before any wave's P writes clobber QP
    }
    if (kt2 < 15) LOADKV((kt2 + 1) * 64)  // latency hides under this iter's compute
    // K A-frags (shared across g)
    s16x8 kf[4][2];
#pragma unroll
    for (int ktile = 0; ktile < 4; ktile++) {
      kf[ktile][0] = frag8((const char*)Ks + (ktile * 16 + col) * 144 + quad * 16);
      kf[ktile][1] = frag8((const char*)Ks + (ktile * 16 + col) * 144 + 64 + quad * 16);
    }
    // S^T tiles: rows=key (quad*4+r), cols=q (col); exp2; pack 4 keys -> b64 write
#pragma unroll
    for (int g = 0; g < 2; g++) {
#pragma unroll
      for (int ktile = 0; ktile < 4; ktile++) {
        f32x4 d = fzero;
        d = __builtin_amdgcn_mfma_f32_16x16x32_bf16(kf[ktile][0], qf[g][0], d, 0, 0, 0);
        d = __builtin_amdgcn_mfma_f32_16x16x32_bf16(kf[ktile][1], qf[g][1], d, 0, 0, 0);
        float p0 = fexp2(d[0]), p1 = fexp2(d[1]), p2 = fexp2(d[2]), p3 = fexp2(d[3]);
        lr[g] += (p0 + p1) + (p2 + p3);
        u16x4 pk = {f2bu(p0), f2bu(p1), f2bu(p2), f2bu(p3)};
        *(u16x4*)(Pw + (g * 16 + col) * 144 + ktile * 32 + quad * 8) = pk;
      }
    }
    // V A-frags (shared across g)
    s16x8 vf[4][2];
#pragma unroll
    for (int jm = 0; jm < 4; jm++) {
      vf[jm][0] = frag8((const char*)Vs + (jm * 16 + col) * 144 + quad * 16);
      vf[jm][1] = frag8((const char*)Vs + (jm * 16 + col) * 144 + 64 + quad * 16);
    }
    // O^T += V^T P^T (P re-read as B-operand; same-wave DS ops are in-order)
#pragma unroll
    for (int g = 0; g < 2; g++) {
      s16x8 pf0 = frag8(Pw + (g * 16 + col) * 144 + quad * 16);
      s16x8 pf1 = frag8(Pw + (g * 16 + col) * 144 + 64 + quad * 16);
#pragma unroll
      for (int jm = 0; jm < 4; jm++) {
        o[g][jm] = __builtin_amdgcn_mfma_f32_16x16x32_bf16(vf[jm][0], pf0, o[g][jm], 0, 0, 0);
        o[g][jm] = __builtin_amdgcn_mfma_f32_16x16x32_bf16(vf[jm][1], pf1, o[g][jm], 0, 0, 0);
      }
    }
  }
#undef LOADKV
#undef WRITEKV
  // l lives per (q=col): quads hold disjoint key subsets -> reduce across quads
#pragma unroll
  for (int g = 0; g < 2; g++) {
    lr[g] += __shfl_xor(lr[g], 16, 64);
    lr[g] += __shfl_xor(lr[g], 32, 64);
  }
  // normalize + packed store: row = q, 4 consecutive d per lane -> 8B stores
#pragma unroll
  for (int g = 0; g < 2; g++) {
    float invl = 1.f / lr[g];
    size_t grow = qrow0 + g * 64 + wave * 16 + col;
    char* obase = (char*)(Oa + grow * E_ + h * DH_);
#pragma unroll
    for (int jm = 0; jm < 4; jm++) {
      u16x4 pk = {f2bu(o[g][jm][0] * invl), f2bu(o[g][jm][1] * invl),
                  f2bu(o[g][jm][2] * invl), f2bu(o[g][jm][3] * invl)};
      *(u16x4*)(obase + jm * 32 + quad * 8) = pk;
    }
  }
}

extern "C" void kernel_launch(void* const* d_in, const int* in_sizes, int n_in,
                              void* d_out, int out_size, void* d_ws, size_t ws_size,
                              hipStream_t stream) {
  const float* X   = (const float*)d_in[0];
  const int*   pos = (const int*)d_in[1];
  const float* Wq  = (const float*)d_in[2];
  const float* bq  = (const float*)d_in[3];
  const float* Wk  = (const float*)d_in[4];
  const float* bk  = (const float*)d_in[5];
  const float* Wv  = (const float*)d_in[6];
  const float* bv  = (const float*)d_in[7];
  const float* Wo  = (const float*)d_in[8];
  const float* bo  = (const float*)d_in[9];
  float* out = (float*)d_out;

  char* ws = (char*)d_ws;
  const size_t MB = 1024 * 1024;
  __hip_bfloat16* Xb    = (__hip_bfloat16*)(ws + 0 * MB);    // 32 MB
  __hip_bfloat16* Qb    = (__hip_bfloat16*)(ws + 32 * MB);   // 32 MB
  __hip_bfloat16* Kb    = (__hip_bfloat16*)(ws + 64 * MB);   // 32 MB
  __hip_bfloat16* Vtb   = (__hip_bfloat16*)(ws + 96 * MB);   // 32 MB (b,h,d,t)
  __hip_bfloat16* Wqkvb = (__hip_bfloat16*)(ws + 128 * MB);  // 6 MB (3072x1024)
  __hip_bfloat16* Wob   = (__hip_bfloat16*)(ws + 136 * MB);  // 2 MB
  __hip_bfloat16* Ab    = Xb;  // reuse: X dead after QKV projection

  cast_all<<<20480, 256, 0, stream>>>(X, Wq, Wk, Wv, Wo, Xb, Wqkvb, Wob);

  gemm_qkv<<<768, 512, 0, stream>>>(Xb, Wqkvb, bq, bk, bv, pos, Qb, Kb, Vtb);

  attn_flash<<<2048, 256, 0, stream>>>(Qb, Kb, Vtb, Ab);

  gemm_out<<<256, 512, 0, stream>>>(Ab, Wob, bo, out);
}

// Round 3
// 366.194 us; speedup vs baseline: 1.2357x; 1.1845x over previous
//
#include <hip/hip_runtime.h>
#include <hip/hip_bf16.h>

// CLIPAttention (B=16,T=1024,E=1024,H=16,DH=64) with 2D RoPE, bf16 MFMA path.
#define B_  16
#define T_  1024
#define E_  1024
#define H_  16
#define DH_ 64

typedef short s16x8 __attribute__((ext_vector_type(8)));   // 8 bf16 = 4 VGPRs (MFMA A/B frag)
typedef float f32x4 __attribute__((ext_vector_type(4)));   // MFMA C/D frag
typedef unsigned short u16x4 __attribute__((ext_vector_type(4)));  // 4 bf16 = 8B

__device__ __forceinline__ void async_cp16(const void* g, void* l) {
  __builtin_amdgcn_global_load_lds(
      (__attribute__((address_space(1))) unsigned int*)(g),
      (__attribute__((address_space(3))) unsigned int*)(l), 16, 0, 0);
}

__device__ __forceinline__ s16x8 frag8(const void* p) { return *(const s16x8*)p; }

__device__ __forceinline__ float fexp2(float x) {
#if __has_builtin(__builtin_amdgcn_exp2f)
  return __builtin_amdgcn_exp2f(x);
#else
  return exp2f(x);
#endif
}

__device__ __forceinline__ unsigned short f2bu(float x) {
  __hip_bfloat16 h = __float2bfloat16(x);
  return *reinterpret_cast<unsigned short*>(&h);
}

// ---------------- single fused cast fp32 -> bf16 (X + 4 weight mats) ----------------
__global__ __launch_bounds__(256) void cast_all(const float* __restrict__ X,
                                                const float* __restrict__ Wq,
                                                const float* __restrict__ Wk,
                                                const float* __restrict__ Wv,
                                                const float* __restrict__ Wo,
                                                __hip_bfloat16* __restrict__ Xb,
                                                __hip_bfloat16* __restrict__ Wqkvb,
                                                __hip_bfloat16* __restrict__ Wob) {
  const int bid = blockIdx.x;
  const float* src;
  __hip_bfloat16* dst;
  int i;
  if (bid < 16384) {
    src = X; dst = Xb; i = bid * 256 + threadIdx.x;
  } else {
    const int wb = bid - 16384;
    const int w = wb >> 10;
    src = (w == 0) ? Wq : (w == 1) ? Wk : (w == 2) ? Wv : Wo;
    dst = (w == 3) ? Wob : Wqkvb + (size_t)w * 1048576;
    i = (wb & 1023) * 256 + threadIdx.x;
  }
  float4 v = ((const float4*)src)[i];
  u16x4 pk = {f2bu(v.x), f2bu(v.y), f2bu(v.z), f2bu(v.w)};
  *(u16x4*)(dst + (size_t)i * 4) = pk;
}

// ======================================================================
// 256x256 8-phase GEMM core (T1+T2+T3+T4+T5), BK=64, 512 threads = 8 waves (2Mx4N).
// (unchanged - verified correct across R1/R2)
// ======================================================================
#define G8_ISSUE(SRC_, LOFF_, H_, D_, KT_)                                      \
  {                                                                             \
    _Pragma("unroll") for (int u_ = 0; u_ < 2; ++u_) {                          \
      const int ch_ = u_ * 8 + wave;                                            \
      async_cp16(SRC_ + (size_t)((H_)*128 + ch_ * 8) * 2048 + (KT_)*128,        \
                 smem + (D_)*65536 + (LOFF_) + (H_)*16384 + ch_ * 1024);        \
    }                                                                           \
  }

#define G8_READ_A(D_, S_)                                                       \
  {                                                                             \
    _Pragma("unroll") for (int i_ = 0; i_ < 4; ++i_) {                          \
      const char* rp_ = smem + (D_)*65536 + wrow * 16384 +                      \
                        ((S_)*64 + i_ * 16 + col) * 128;                        \
      af[i_][0] = frag8(rp_ + sw0);                                             \
      af[i_][1] = frag8(rp_ + sw1);                                             \
    }                                                                           \
  }

#define G8_READ_B(D_, T8_, BF_)                                                 \
  {                                                                             \
    _Pragma("unroll") for (int j_ = 0; j_ < 2; ++j_) {                          \
      const char* rp_ = smem + (D_)*65536 + 32768 + (wcol >> 1) * 16384 +       \
                        ((wcol & 1) * 64 + (T8_)*32 + j_ * 16 + col) * 128;     \
      BF_[j_][0] = frag8(rp_ + sw0);                                            \
      BF_[j_][1] = frag8(rp_ + sw1);                                            \
    }                                                                           \
  }

#define G8_MFMA(S_, T8_, BF_)                                                   \
  {                                                                             \
    __builtin_amdgcn_s_setprio(1);                                              \
    _Pragma("unroll") for (int i_ = 0; i_ < 4; ++i_)                            \
      _Pragma("unroll") for (int j_ = 0; j_ < 2; ++j_) {                        \
        acc[(S_)*4 + i_][(T8_)*2 + j_] = __builtin_amdgcn_mfma_f32_16x16x32_bf16( \
            af[i_][0], BF_[j_][0], acc[(S_)*4 + i_][(T8_)*2 + j_], 0, 0, 0);    \
        acc[(S_)*4 + i_][(T8_)*2 + j_] = __builtin_amdgcn_mfma_f32_16x16x32_bf16( \
            af[i_][1], BF_[j_][1], acc[(S_)*4 + i_][(T8_)*2 + j_], 0, 0, 0);    \
      }                                                                         \
    __builtin_amdgcn_s_setprio(0);                                              \
  }

#define G8_KTILE(D_, GA_, GB_, KTA_, KTB_, VM_)                                 \
  G8_READ_A(D_, 0)                                                              \
  G8_READ_B(D_, 0, bf0)                                                         \
  if (GA_) G8_ISSUE(Asrc, 0, 0, (D_) ^ 1, KTA_)                                 \
  __builtin_amdgcn_s_barrier();                                                 \
  G8_MFMA(0, 0, bf0)                                                            \
  __builtin_amdgcn_s_barrier();                                                 \
  G8_READ_B(D_, 1, bf1)                                                         \
  if (GA_) G8_ISSUE(Asrc, 0, 1, (D_) ^ 1, KTA_)                                 \
  __builtin_amdgcn_s_barrier();                                                 \
  G8_MFMA(0, 1, bf1)                                                            \
  __builtin_amdgcn_s_barrier();                                                 \
  G8_READ_A(D_, 1)                                                              \
  if (GB_) G8_ISSUE(Bsrc, 32768, 0, (D_), KTB_)                                 \
  __builtin_amdgcn_s_barrier();                                                 \
  G8_MFMA(1, 1, bf1)                                                            \
  __builtin_amdgcn_s_barrier();                                                 \
  if (GB_) G8_ISSUE(Bsrc, 32768, 1, (D_), KTB_)                                 \
  __builtin_amdgcn_s_barrier();                                                 \
  G8_MFMA(1, 0, bf0)                                                            \
  if (VM_) { asm volatile("s_waitcnt vmcnt(4)" ::: "memory"); }                 \
  else     { asm volatile("s_waitcnt vmcnt(0)" ::: "memory"); }                 \
  __builtin_amdgcn_s_barrier();

#define G8_CORE(APTR_, BPTR_)                                                   \
  __shared__ __align__(16) char smem[131072];                                   \
  const int tid = threadIdx.x;                                                  \
  const int lane = tid & 63, wave = tid >> 6;                                   \
  const int col = lane & 15, quad = lane >> 4;                                  \
  const int wrow = wave >> 2, wcol = wave & 3;                                  \
  const int r8 = lane >> 3;                                                     \
  const int gsw = (lane & 7) ^ r8;                                              \
  const int sw0 = (quad ^ (col & 7)) * 16;                                      \
  const int sw1 = ((quad + 4) ^ (col & 7)) * 16;                                \
  const char* Asrc = (const char*)(APTR_) + (size_t)(bm + r8) * 2048 + gsw * 16;\
  const char* Bsrc = (const char*)(BPTR_) + (size_t)(bn + r8) * 2048 + gsw * 16;\
  const f32x4 fzero = {0.f, 0.f, 0.f, 0.f};                                     \
  f32x4 acc[8][4];                                                              \
  _Pragma("unroll") for (int i_ = 0; i_ < 8; i_++)                              \
    _Pragma("unroll") for (int j_ = 0; j_ < 4; j_++) acc[i_][j_] = fzero;       \
  s16x8 af[4][2], bf0[2][2], bf1[2][2];                                         \
  G8_ISSUE(Bsrc, 32768, 0, 0, 0)                                                \
  G8_ISSUE(Bsrc, 32768, 1, 0, 0)                                                \
  G8_ISSUE(Asrc, 0, 0, 0, 0)                                                    \
  G8_ISSUE(Asrc, 0, 1, 0, 0)                                                    \
  G8_ISSUE(Bsrc, 32768, 0, 1, 1)                                                \
  G8_ISSUE(Bsrc, 32768, 1, 1, 1)                                                \
  asm volatile("s_waitcnt vmcnt(4)" ::: "memory");                              \
  __builtin_amdgcn_s_barrier();                                                 \
  _Pragma("clang loop unroll(disable)") for (int it = 0; it < 8; ++it) {        \
    const bool g7 = (it < 7);                                                   \
    G8_KTILE(0, true, g7, 2 * it + 1, 2 * it + 2, g7)                           \
    G8_KTILE(1, g7, g7, 2 * it + 2, 2 * it + 3, g7)                             \
  }

// ---------------- fused QKV GEMM + bias + 2D RoPE epilogue ----------------
__global__ __launch_bounds__(512, 2) void gemm_qkv(const __hip_bfloat16* __restrict__ A,
                                                   const __hip_bfloat16* __restrict__ Wqkv,
                                                   const float* __restrict__ bq,
                                                   const float* __restrict__ bk,
                                                   const float* __restrict__ bv,
                                                   const int* __restrict__ pos,
                                                   __hip_bfloat16* __restrict__ Qb,
                                                   __hip_bfloat16* __restrict__ Kb,
                                                   __hip_bfloat16* __restrict__ Vt) {
  const int wg = (blockIdx.x & 7) * 96 + (blockIdx.x >> 3);  // XCD swizzle (768%8==0)
  const int bm = (wg & 63) << 8;
  const int bn = (wg >> 6) << 8;
  G8_CORE(A, Wqkv)

  const int seg = bn >> 10;  // 0=Q 1=K 2=V (BN=256 divides 1024 -> uniform per block)
  const float* bp = (seg == 0) ? bq : (seg == 1) ? bk : bv;
  const int nbase = (bn & 1023) + wcol * 64;
  float bcol[4];
#pragma unroll
  for (int j = 0; j < 4; j++) bcol[j] = bp[nbase + j * 16 + col];
  if (seg < 2) {
    // ---- build sincos table in freed smem: tab[p*16+f] = {cos, sin} of p*10000^(-f/8)
    __syncthreads();
    float2* tab = (float2*)smem;
    {
      const int p_ = tid >> 4, f_ = tid & 15;
      const float inv = __expf((float)f_ * -1.1512925464970229f);
      float s_, c_;
      __sincosf((float)p_ * inv, &s_, &c_);
      tab[tid] = make_float2(c_, s_);
    }
    __syncthreads();
    const float SCL = (seg == 0) ? 0.18033688011112043f : 1.0f;  // Q: 0.125*log2(e)
    __hip_bfloat16* P = (seg == 0) ? Qb : Kb;
    const int codd = col & 1;
#pragma unroll
    for (int mi = 0; mi < 8; mi++) {
      const int gr0 = bm + wrow * 128 + mi * 16 + quad * 4;
#pragma unroll
      for (int r = 0; r < 4; r++) {
        const int grow = gr0 + r;
        const int iph = pos[grow * 2 + 0];
        const int ipw = pos[grow * 2 + 1];
#pragma unroll
        for (int ni = 0; ni < 4; ni++) {
          const int f = ((ni & 1) << 3) + (col >> 1);
          const int p_ = (ni >= 2) ? ipw : iph;
          const float2 cs = tab[p_ * 16 + f];
          const float v = acc[mi][ni][r] + bcol[ni];
          const float vp = __shfl_xor(v, 1, 64);
          const float rot = codd ? (v * cs.x + vp * cs.y) : (v * cs.x - vp * cs.y);
          P[(size_t)grow * 1024 + nbase + ni * 16 + col] = __float2bfloat16(rot * SCL);
        }
      }
    }
  } else {
    // V transposed (b,h,d,t): 4 consecutive t per lane -> packed 8B store
#pragma unroll
    for (int mi = 0; mi < 8; mi++) {
      const int gr0 = bm + wrow * 128 + mi * 16 + quad * 4;
      const int bb = gr0 >> 10, tt = gr0 & 1023;
#pragma unroll
      for (int ni = 0; ni < 4; ni++) {
        const int nc = nbase + ni * 16 + col;
        const int hh = nc >> 6, dd = nc & 63;
        u16x4 pk = {f2bu(acc[mi][ni][0] + bcol[ni]), f2bu(acc[mi][ni][1] + bcol[ni]),
                    f2bu(acc[mi][ni][2] + bcol[ni]), f2bu(acc[mi][ni][3] + bcol[ni])};
        *(u16x4*)(Vt + (((size_t)bb * H_ + hh) * DH_ + dd) * T_ + tt) = pk;
      }
    }
  }
}

// ---------------- output-proj GEMM: fp32 out (grid 64x4=256) ----------------
__global__ __launch_bounds__(512, 2) void gemm_out(const __hip_bfloat16* __restrict__ A,
                                                   const __hip_bfloat16* __restrict__ Bw,
                                                   const float* __restrict__ bias,
                                                   float* __restrict__ Cout) {
  const int wg = (blockIdx.x & 7) * 32 + (blockIdx.x >> 3);  // XCD swizzle (256%8==0)
  const int bm = (wg & 63) << 8;
  const int bn = (wg >> 6) << 8;
  G8_CORE(A, Bw)

  const int nbase = bn + wcol * 64;
  float bcol[4];
#pragma unroll
  for (int j = 0; j < 4; j++) bcol[j] = bias[nbase + j * 16 + col];
#pragma unroll
  for (int mi = 0; mi < 8; mi++) {
    const int gr0 = bm + wrow * 128 + mi * 16 + quad * 4;
#pragma unroll
    for (int ni = 0; ni < 4; ni++) {
      const int gcol = nbase + ni * 16 + col;
#pragma unroll
      for (int r = 0; r < 4; r++)
        Cout[(size_t)(gr0 + r) * 1024 + gcol] = acc[mi][ni][r] + bcol[ni];
    }
  }
}

// ---------------- flash attention, S^T formulation, fixed-max softmax ----------------
// R3: K/V staged via global_load_lds into DOUBLE-BUFFERED XOR-swizzled 128B-pitch
// LDS (GEMM-proven layout: group g of row r at g^(r&7); frag reads use sw0/sw1 ->
// conflict-free, fixes the 14.8M bank conflicts of the 144B-pitch layout).
// Stage for tile k+1 issued at TOP of iter k; the single __syncthreads per iter
// (drains vmcnt+lgkmcnt) publishes the buffer and protects the swap. No serial
// staging phase; load latency hides under the whole iteration's compute.
// XCD-locality swizzle kept (FETCH 278->56 MB verified in R2).
__global__ __launch_bounds__(256, 3) void attn_flash(const __hip_bfloat16* __restrict__ Q,
                                                     const __hip_bfloat16* __restrict__ Kt,
                                                     const __hip_bfloat16* __restrict__ Vt,
                                                     __hip_bfloat16* __restrict__ Oa) {
  __shared__ __align__(16) __hip_bfloat16 QP[128 * 72];  // 18432B: Q tile / P^T scratch, 144B pitch
  __shared__ __align__(16) char KV[2][2][8192];          // [buf][K|V][64 rows x 128B, XOR-swizzled]

  const int bid = blockIdx.x;          // 2048 = 256 (b,h) x 8 q-tiles
  const int xcd = bid & 7, slot = bid >> 3;
  const int bh = xcd * 32 + (slot >> 3);   // all 8 q-tiles + 32 bh share an XCD
  const int qt = slot & 7;
  const int b = bh >> 4, h = bh & 15;
  const int tid = threadIdx.x;
  const int lane = tid & 63, wave = tid >> 6;
  const int col = lane & 15, quad = lane >> 4;
  const int r8 = lane >> 3;
  const int gsw = ((lane & 7) ^ r8) * 16;              // global-side XOR pre-swizzle
  const int sw0 = (quad ^ (col & 7)) * 16;             // LDS-side frag-read swizzle
  const int sw1 = ((quad + 4) ^ (col & 7)) * 16;

  const size_t qrow0 = (size_t)b * T_ + qt * 128;

  // K/V staging: wave w covers chunks {w, w+4} of both K and V (16x 1KB cp16 per tile)
  const char* Kbase = (const char*)(Kt + (size_t)b * T_ * E_ + h * DH_);
  const char* Vbase = (const char*)(Vt + ((size_t)b * H_ + h) * DH_ * (size_t)T_);
#define STAGE_KV(KB_, D_)                                                          \
  {                                                                                \
    _Pragma("unroll") for (int u_ = 0; u_ < 2; ++u_) {                             \
      const int ch_ = u_ * 4 + wave;                                               \
      async_cp16(Kbase + (size_t)((KB_) + ch_ * 8 + r8) * 2048 + gsw,              \
                 &KV[D_][0][ch_ * 1024]);                                          \
      async_cp16(Vbase + (size_t)(ch_ * 8 + r8) * 2048 + (KB_)*2 + gsw,            \
                 &KV[D_][1][ch_ * 1024]);                                          \
    }                                                                              \
  }

  STAGE_KV(0, 0)
  // stage Q tile (128 rows x 128B) into padded QP
#pragma unroll
  for (int cc = 0; cc < 4; ++cc) {
    int c = tid + cc * 256;
    int r = c >> 3, k8 = c & 7;
    const float4* src = (const float4*)((const char*)(Q + (qrow0 + r) * E_ + h * DH_)) + k8;
    *(float4*)((char*)QP + r * 144 + k8 * 16) = *src;
  }
  __syncthreads();  // drains own vmcnt (cp16 tile0) + lgkm; Q visible

  // Q frags once, then protect QP before P writes clobber it
  s16x8 qf[2][2];
#pragma unroll
  for (int g = 0; g < 2; g++) {
    qf[g][0] = frag8((const char*)QP + (g * 64 + wave * 16 + col) * 144 + quad * 16);
    qf[g][1] = frag8((const char*)QP + (g * 64 + wave * 16 + col) * 144 + 64 + quad * 16);
  }
  __syncthreads();

  const f32x4 fzero = {0.f, 0.f, 0.f, 0.f};
  f32x4 o[2][4];           // o[g][jm][r] = O^T[d = jm*16+quad*4+r][q = col]
  float lr[2] = {0.f, 0.f};
#pragma unroll
  for (int g = 0; g < 2; g++)
#pragma unroll
    for (int j = 0; j < 4; j++) o[g][j] = fzero;
  char* Pw = (char*)QP + wave * 32 * 144;  // this wave's 32 P rows (q-major, 144B pitch)

  for (int kt2 = 0; kt2 < 16; ++kt2) {
    const int d = kt2 & 1;
    if (kt2 < 15) STAGE_KV((kt2 + 1) * 64, d ^ 1)  // fills other buffer; waited at iter-end sync
    // K A-frags (shared across g), conflict-free XOR reads
    s16x8 kf[4][2];
#pragma unroll
    for (int ktile = 0; ktile < 4; ktile++) {
      const char* kp = &KV[d][0][(ktile * 16 + col) * 128];
      kf[ktile][0] = frag8(kp + sw0);
      kf[ktile][1] = frag8(kp + sw1);
    }
    // S^T tiles: rows=key (quad*4+r), cols=q (col); exp2; pack 4 keys -> b64 write
#pragma unroll
    for (int g = 0; g < 2; g++) {
#pragma unroll
      for (int ktile = 0; ktile < 4; ktile++) {
        f32x4 dacc = fzero;
        dacc = __builtin_amdgcn_mfma_f32_16x16x32_bf16(kf[ktile][0], qf[g][0], dacc, 0, 0, 0);
        dacc = __builtin_amdgcn_mfma_f32_16x16x32_bf16(kf[ktile][1], qf[g][1], dacc, 0, 0, 0);
        float p0 = fexp2(dacc[0]), p1 = fexp2(dacc[1]), p2 = fexp2(dacc[2]), p3 = fexp2(dacc[3]);
        lr[g] += (p0 + p1) + (p2 + p3);
        u16x4 pk = {f2bu(p0), f2bu(p1), f2bu(p2), f2bu(p3)};
        *(u16x4*)(Pw + (g * 16 + col) * 144 + ktile * 32 + quad * 8) = pk;
      }
    }
    // V A-frags, conflict-free XOR reads
    s16x8 vf[4][2];
#pragma unroll
    for (int jm = 0; jm < 4; jm++) {
      const char* vp = &KV[d][1][(jm * 16 + col) * 128];
      vf[jm][0] = frag8(vp + sw0);
      vf[jm][1] = frag8(vp + sw1);
    }
    // O^T += V^T P^T (P re-read as B-operand; same-wave DS ops are in-order)
#pragma unroll
    for (int g = 0; g < 2; g++) {
      s16x8 pf0 = frag8(Pw + (g * 16 + col) * 144 + quad * 16);
      s16x8 pf1 = frag8(Pw + (g * 16 + col) * 144 + 64 + quad * 16);
#pragma unroll
      for (int jm = 0; jm < 4; jm++) {
        o[g][jm] = __builtin_amdgcn_mfma_f32_16x16x32_bf16(vf[jm][0], pf0, o[g][jm], 0, 0, 0);
        o[g][jm] = __builtin_amdgcn_mfma_f32_16x16x32_bf16(vf[jm][1], pf1, o[g][jm], 0, 0, 0);
      }
    }
    __syncthreads();  // drains cp16 (next buf ready) + all waves' LDS reads (swap safe)
  }
#undef STAGE_KV
  // l lives per (q=col): quads hold disjoint key subsets -> reduce across quads
#pragma unroll
  for (int g = 0; g < 2; g++) {
    lr[g] += __shfl_xor(lr[g], 16, 64);
    lr[g] += __shfl_xor(lr[g], 32, 64);
  }
  // normalize + packed store: row = q, 4 consecutive d per lane -> 8B stores
#pragma unroll
  for (int g = 0; g < 2; g++) {
    float invl = 1.f / lr[g];
    size_t grow = qrow0 + g * 64 + wave * 16 + col;
    char* obase = (char*)(Oa + grow * E_ + h * DH_);
#pragma unroll
    for (int jm = 0; jm < 4; jm++) {
      u16x4 pk = {f2bu(o[g][jm][0] * invl), f2bu(o[g][jm][1] * invl),
                  f2bu(o[g][jm][2] * invl), f2bu(o[g][jm][3] * invl)};
      *(u16x4*)(obase + jm * 32 + quad * 8) = pk;
    }
  }
}

extern "C" void kernel_launch(void* const* d_in, const int* in_sizes, int n_in,
                              void* d_out, int out_size, void* d_ws, size_t ws_size,
                              hipStream_t stream) {
  const float* X   = (const float*)d_in[0];
  const int*   pos = (const int*)d_in[1];
  const float* Wq  = (const float*)d_in[2];
  const float* bq  = (const float*)d_in[3];
  const float* Wk  = (const float*)d_in[4];
  const float* bk  = (const float*)d_in[5];
  const float* Wv  = (const float*)d_in[6];
  const float* bv  = (const float*)d_in[7];
  const float* Wo  = (const float*)d_in[8];
  const float* bo  = (const float*)d_in[9];
  float* out = (float*)d_out;

  char* ws = (char*)d_ws;
  const size_t MB = 1024 * 1024;
  __hip_bfloat16* Xb    = (__hip_bfloat16*)(ws + 0 * MB);    // 32 MB
  __hip_bfloat16* Qb    = (__hip_bfloat16*)(ws + 32 * MB);   // 32 MB
  __hip_bfloat16* Kb    = (__hip_bfloat16*)(ws + 64 * MB);   // 32 MB
  __hip_bfloat16* Vtb   = (__hip_bfloat16*)(ws + 96 * MB);   // 32 MB (b,h,d,t)
  __hip_bfloat16* Wqkvb = (__hip_bfloat16*)(ws + 128 * MB);  // 6 MB (3072x1024)
  __hip_bfloat16* Wob   = (__hip_bfloat16*)(ws + 136 * MB);  // 2 MB
  __hip_bfloat16* Ab    = Xb;  // reuse: X dead after QKV projection

  cast_all<<<20480, 256, 0, stream>>>(X, Wq, Wk, Wv, Wo, Xb, Wqkvb, Wob);

  gemm_qkv<<<768, 512, 0, stream>>>(Xb, Wqkvb, bq, bk, bv, pos, Qb, Kb, Vtb);

  attn_flash<<<2048, 256, 0, stream>>>(Qb, Kb, Vtb, Ab);

  gemm_out<<<256, 512, 0, stream>>>(Ab, Wob, bo, out);
}